// Round 3
// baseline (16447.275 us; speedup 1.0000x reference)
//
#include <hip/hip_runtime.h>

typedef unsigned short u16;
typedef unsigned int   u32;
typedef unsigned long long u64;

#define LTC_B 32
#define LTC_L 1024
#define LTC_D 512
#define LTC_H 512
#define NG 8               // groups (one per XCD under blockIdx%8 round-robin)
#define NP 16              // producer WGs per group; wave owns 8 rec + 8 gate rows (same 8 cols)
#define NBG 4              // batches per group

typedef _Float16 f16x8  __attribute__((ext_vector_type(8)));
typedef _Float16 f16x2t __attribute__((ext_vector_type(2)));
typedef float    f32x4  __attribute__((ext_vector_type(4)));

static __device__ __forceinline__ u32 packh(float a, float b) {
    f16x2t p; p[0] = (_Float16)a; p[1] = (_Float16)b;
    return __builtin_bit_cast(u32, p);
}
static __device__ __forceinline__ float unplo(u32 w) {
    return (float)__builtin_bit_cast(f16x2t, w)[0];
}
static __device__ __forceinline__ float unphi(u32 w) {
    return (float)__builtin_bit_cast(f16x2t, w)[1];
}
static __device__ __forceinline__ f16x8 cvt8(const float* p) {
    const float4 a = *(const float4*)p;
    const float4 b = *(const float4*)(p + 4);
    f16x8 r;
    r[0] = (_Float16)a.x; r[1] = (_Float16)a.y; r[2] = (_Float16)a.z; r[3] = (_Float16)a.w;
    r[4] = (_Float16)b.x; r[5] = (_Float16)b.y; r[6] = (_Float16)b.z; r[7] = (_Float16)b.w;
    return r;
}
static __device__ __forceinline__ bool stamp4(u64 a, u64 b, u64 c, u64 d, u32 k) {
    return ((u32)(a >> 32) == k) & ((u32)(b >> 32) == k) &
           ((u32)(c >> 32) == k) & ((u32)(d >> 32) == k);
}

// ---------------------------------------------------------------------------
// C[M,512](f16) = A[M,512](f32) . W[:,:512]^T(f32, row stride ldb) + bias(f32)
// ---------------------------------------------------------------------------
__global__ __launch_bounds__(256) void gemm_a32_c16(
    const float* __restrict__ A, const float* __restrict__ W, int ldb,
    const float* __restrict__ bias, u16* __restrict__ C)
{
    const int wave = threadIdx.x >> 6;
    const int lane = threadIdx.x & 63;
    const int tile = blockIdx.x * 4 + wave;
    const int nt = tile & 7;
    const int mt = tile >> 3;
    const int r16 = lane & 15;
    const int kq  = (lane >> 4) * 8;

    const float* ap = A + (size_t)(mt * 64 + r16) * LTC_D + kq;
    const float* wp = W + (size_t)(nt * 64 + r16) * ldb + kq;

    f32x4 acc[4][4];
    #pragma unroll
    for (int i = 0; i < 4; ++i)
        #pragma unroll
        for (int jj = 0; jj < 4; ++jj) acc[i][jj] = (f32x4){0.f, 0.f, 0.f, 0.f};

    for (int ks = 0; ks < 16; ++ks) {
        f16x8 af[4], bf[4];
        #pragma unroll
        for (int t = 0; t < 4; ++t) {
            af[t] = cvt8(ap + (size_t)t * 16 * LTC_D + ks * 32);
            bf[t] = cvt8(wp + (size_t)t * 16 * ldb  + ks * 32);
        }
        #pragma unroll
        for (int mi = 0; mi < 4; ++mi)
            #pragma unroll
            for (int ni = 0; ni < 4; ++ni)
                acc[mi][ni] = __builtin_amdgcn_mfma_f32_16x16x32_f16(
                    af[mi], bf[ni], acc[mi][ni], 0, 0, 0);
    }
    const int row = (lane >> 4) * 4;   // C/D: col=lane&15 (n), row=(lane>>4)*4+reg (m)
    const int col = lane & 15;
    #pragma unroll
    for (int ni = 0; ni < 4; ++ni) {
        const int n = nt * 64 + ni * 16 + col;
        const float bv = bias[n];
        #pragma unroll
        for (int mi = 0; mi < 4; ++mi)
            #pragma unroll
            for (int r = 0; r < 4; ++r) {
                _Float16 h = (_Float16)(acc[mi][ni][r] + bv);
                C[(size_t)(mt * 64 + mi * 16 + row + r) * LTC_H + n] =
                    __builtin_bit_cast(u16, h);
            }
    }
}

// ---------------------------------------------------------------------------
// C[M,512](f32) = A[M,512](f16) . W^T(f32, row stride 512) + bias(f32)
// ---------------------------------------------------------------------------
__global__ __launch_bounds__(256) void gemm_a16_c32(
    const u16* __restrict__ A, const float* __restrict__ W,
    const float* __restrict__ bias, float* __restrict__ C)
{
    const int wave = threadIdx.x >> 6;
    const int lane = threadIdx.x & 63;
    const int tile = blockIdx.x * 4 + wave;
    const int nt = tile & 7;
    const int mt = tile >> 3;
    const int r16 = lane & 15;
    const int kq  = (lane >> 4) * 8;

    const _Float16* ap = (const _Float16*)A + (size_t)(mt * 64 + r16) * LTC_D + kq;
    const float*    wp = W + (size_t)(nt * 64 + r16) * LTC_H + kq;

    f32x4 acc[4][4];
    #pragma unroll
    for (int i = 0; i < 4; ++i)
        #pragma unroll
        for (int jj = 0; jj < 4; ++jj) acc[i][jj] = (f32x4){0.f, 0.f, 0.f, 0.f};

    for (int ks = 0; ks < 16; ++ks) {
        f16x8 af[4], bf[4];
        #pragma unroll
        for (int t = 0; t < 4; ++t) {
            af[t] = *(const f16x8*)(ap + (size_t)t * 16 * LTC_D + ks * 32);
            bf[t] = cvt8(wp + (size_t)t * 16 * LTC_H + ks * 32);
        }
        #pragma unroll
        for (int mi = 0; mi < 4; ++mi)
            #pragma unroll
            for (int ni = 0; ni < 4; ++ni)
                acc[mi][ni] = __builtin_amdgcn_mfma_f32_16x16x32_f16(
                    af[mi], bf[ni], acc[mi][ni], 0, 0, 0);
    }
    const int row = (lane >> 4) * 4;
    const int col = lane & 15;
    #pragma unroll
    for (int ni = 0; ni < 4; ++ni) {
        const int n = nt * 64 + ni * 16 + col;
        const float bv = bias[n];
        #pragma unroll
        for (int mi = 0; mi < 4; ++mi)
            #pragma unroll
            for (int r = 0; r < 4; ++r)
                C[(size_t)(mt * 64 + mi * 16 + row + r) * LTC_H + n] =
                    acc[mi][ni][r] + bv;
    }
}

// ---------------------------------------------------------------------------
// ODE scan: 8 groups x 4 batches, 16 producer WGs per group (128 WGs).
// Round-0 work geometry (16 MFMAs/wave, 4-exp chain, 64 update threads)
// WITHOUT the red[] LDS round-trip: each wave's B-operand packs
// [8 W_rec rows ; 8 Wg_h rows] of the SAME 8 columns, so the MFMA output
// holds rec(n) in cols 0-7 and gate(n) in cols 8-15 — both in registers.
// Lanes 0-7 compute tanh(d+rec), lanes 8-15 sigm(gx+gate) (one unified
// a*sigm(b*x)+c exp path, no divergent transcendental code), shfl_xor(8)
// combines, lanes 0-7 update h, shfl_xor(1) packs pairs, even lanes
// publish. One __syncthreads per sub-step (after the gather). Exchange =
// the VALIDATED LLC channel, byte-identical: stamped u64
// (stamp<<32 | f16 pair), relaxed agent-scope publish, batched 4-load LLC
// poll sweep, bounded budget (protocol failure => wrong answer, never a
// hang). hTu parity double-buffer: publish(k) by any wave implies its WG
// passed the end-of-(k-1) barrier, hence finished gather(k-1) and reading
// slot (k-2)&1 == k&1 before it is overwritten.
// ---------------------------------------------------------------------------
__global__ __launch_bounds__(256) void ltc_scan(
    u32* __restrict__ drive,            // f16 pairs; rewritten with fwd
    const u32* __restrict__ gatex,      // f16 pairs
    const float* __restrict__ W_rec,
    const float* __restrict__ W_gate,
    const float* __restrict__ log_tau,
    u64* __restrict__ hbuf,             // [2 par][8 g][4 b][256] stamped pairs
    float* __restrict__ hlast)
{
    const int g   = blockIdx.x & 7;     // group
    const int p   = blockIdx.x >> 3;    // producer slice 0..15
    const int tid = threadIdx.x;
    const int lane = tid & 63;
    const int wv   = tid >> 6;

    __shared__ u32 hTu[2][16][260];     // parity-dbuf h as f16 pairs; rows 0-3 = batches

    // ---- one-time B-fragments: cols j0..j0+7; B rows 0-7 = W_rec(j0+c),
    //      B rows 8-15 = Wg_h(j0+c-8). MFMA output col c<8 -> rec, c>=8 -> gate.
    const int j0 = 32 * p + 8 * wv;     // this wave's 8 columns
    const int c16 = lane & 15;
    const int kq  = (lane >> 4) * 8;

    const float* wrow = (c16 < 8)
        ? (W_rec  + (size_t)(j0 + c16) * LTC_H)
        : (W_gate + (size_t)(j0 + c16 - 8) * (LTC_D + LTC_H) + LTC_D);
    f16x8 Wf[16];
    #pragma unroll
    for (int ks = 0; ks < 16; ++ks) Wf[ks] = cvt8(wrow + ks * 32 + kq);

    for (int i = tid; i < 2 * 16 * 260; i += 256) (&hTu[0][0][0])[i] = 0;  // h0 = 0

    // ---- per-lane update state (lanes 0..15 of every wave)
    //      lane c<8: col n=j0+c, tanh side (needs drive); lane c>=8: col
    //      n=j0+c-8, sigm side (needs gatex).
    const int n = j0 + (lane & 7);      // valid for lane<16
    const int hodd = lane & 1;
    float h[4] = {0.f, 0.f, 0.f, 0.f};
    float stau = 0.f;
    size_t dofs[4] = {0, 0, 0, 0};
    u32 dw[4] = {0, 0, 0, 0};
    const u32* insrc = (lane < 8) ? drive : gatex;
    if (lane < 16) {
        stau = (1.f / 6.f) * __expf(-log_tau[n]);
        #pragma unroll
        for (int r = 0; r < 4; ++r)
            dofs[r] = (size_t)(g * NBG + r) * LTC_L * 256 + (n >> 1);
        #pragma unroll
        for (int r = 0; r < 4; ++r) dw[r] = insrc[dofs[r]];
    }
    __syncthreads();

    const u32* hbase = &hTu[0][c16][(lane >> 4) * 4];
    u32 kp1 = 0;
    int budget = 1 << 22;               // global failing-poll budget (no hangs)

    const float fa = (lane & 8) ? 1.f : 2.f;     // sigm : tanh=2*sigm(2x)-1
    const float fb = (lane & 8) ? -1.f : -2.f;
    const float fc = (lane & 8) ? 0.f : -1.f;

    for (int l = 0; l < LTC_L; ++l) {
        float in_[4];
        if (lane < 16) {
            #pragma unroll
            for (int r = 0; r < 4; ++r)
                in_[r] = hodd ? unphi(dw[r]) : unplo(dw[r]);
        }
        // prefetch next step's inputs (overlaps with 6 sub-steps of work)
        u32 dn_[4] = {0, 0, 0, 0};
        if (lane < 16 && l + 1 < LTC_L) {
            #pragma unroll
            for (int r = 0; r < 4; ++r)
                dn_[r] = insrc[dofs[r] + (size_t)(l + 1) * 256];
        }
        u32 pw[4] = {0, 0, 0, 0};
        #pragma unroll 1
        for (int s = 0; s < 6; ++s) {
            // ---- matvec: 16 MFMAs, 2 chains; output col c<8 rec, c>=8 gate
            const u32* hb = hbase + (kp1 & 1u) * (16 * 260);
            f32x4 acc0 = (f32x4){0.f, 0.f, 0.f, 0.f};
            f32x4 acc1 = acc0;
            #pragma unroll
            for (int ks = 0; ks < 16; ks += 2) {
                const f16x8 a0 = *(const f16x8*)(hb + ks * 16);
                const f16x8 a1 = *(const f16x8*)(hb + ks * 16 + 16);
                acc0 = __builtin_amdgcn_mfma_f32_16x16x32_f16(a0, Wf[ks],     acc0, 0, 0, 0);
                acc1 = __builtin_amdgcn_mfma_f32_16x16x32_f16(a1, Wf[ks + 1], acc1, 0, 0, 0);
            }
            ++kp1;
            const size_t pbase = (size_t)((kp1 & 1u) * NG + g) * (NBG * 256);
            // ---- in-register update + single LLC publish (fire-and-forget)
            if (lane < 16) {
                float f[4];
                #pragma unroll
                for (int r = 0; r < 4; ++r) {
                    const float arg = in_[r] + acc0[r] + acc1[r];
                    const float e = __expf(fb * arg);     // inf-safe
                    f[r] = fa / (1.f + e) + fc;
                }
                #pragma unroll
                for (int r = 0; r < 4; ++r) {
                    const float sg = __shfl_xor(f[r], 8); // lanes<8 get sigm
                    if (lane < 8) h[r] += stau * (sg * f[r] - h[r]);
                }
                const float e0 = __shfl_xor(h[0], 1);
                const float e1 = __shfl_xor(h[1], 1);
                const float e2 = __shfl_xor(h[2], 1);
                const float e3 = __shfl_xor(h[3], 1);
                if (lane < 8 && !hodd) {
                    pw[0] = packh(h[0], e0); pw[1] = packh(h[1], e1);
                    pw[2] = packh(h[2], e2); pw[3] = packh(h[3], e3);
                    const u64 st = (u64)kp1 << 32;
                    u64* pb = hbuf + pbase + (n >> 1);
                    __hip_atomic_store(pb,       st | pw[0], __ATOMIC_RELAXED,
                                       __HIP_MEMORY_SCOPE_AGENT);
                    __hip_atomic_store(pb + 256, st | pw[1], __ATOMIC_RELAXED,
                                       __HIP_MEMORY_SCOPE_AGENT);
                    __hip_atomic_store(pb + 512, st | pw[2], __ATOMIC_RELAXED,
                                       __HIP_MEMORY_SCOPE_AGENT);
                    __hip_atomic_store(pb + 768, st | pw[3], __ATOMIC_RELAXED,
                                       __HIP_MEMORY_SCOPE_AGENT);
                }
            }
            // ---- gather: column tid across 4 batch rows, batched LLC sweep --
            {
                const u64* sb = hbuf + pbase + tid;
                u64 a0, a1, a2, a3;
                bool ok;
                do {
                    a0 = __hip_atomic_load(sb,       __ATOMIC_RELAXED,
                                           __HIP_MEMORY_SCOPE_AGENT);
                    a1 = __hip_atomic_load(sb + 256, __ATOMIC_RELAXED,
                                           __HIP_MEMORY_SCOPE_AGENT);
                    a2 = __hip_atomic_load(sb + 512, __ATOMIC_RELAXED,
                                           __HIP_MEMORY_SCOPE_AGENT);
                    a3 = __hip_atomic_load(sb + 768, __ATOMIC_RELAXED,
                                           __HIP_MEMORY_SCOPE_AGENT);
                    ok = stamp4(a0, a1, a2, a3, kp1);
                } while (!ok && --budget > 0);
                u32* ht = &hTu[kp1 & 1u][0][0];
                ht[tid]       = (u32)a0;
                ht[260 + tid] = (u32)a1;
                ht[520 + tid] = (u32)a2;
                ht[780 + tid] = (u32)a3;
            }
            __syncthreads();
        }
        if (lane < 8 && !hodd) {        // fwd: reuse last sub-step's packed pairs
            #pragma unroll
            for (int r = 0; r < 4; ++r)
                drive[dofs[r] + (size_t)l * 256] = pw[r];
        }
        #pragma unroll
        for (int r = 0; r < 4; ++r) dw[r] = dn_[r];
    }
    if (lane < 8) {
        #pragma unroll
        for (int r = 0; r < 4; ++r)
            hlast[(size_t)(g * NBG + r) * LTC_H + n] = h[r];
    }
}

// ---------------------------------------------------------------------------
extern "C" void kernel_launch(void* const* d_in, const int* in_sizes, int n_in,
                              void* d_out, int out_size, void* d_ws, size_t ws_size,
                              hipStream_t stream)
{
    const float* x       = (const float*)d_in[0];
    const float* log_tau = (const float*)d_in[1];
    const float* W_in    = (const float*)d_in[2];
    const float* b_in    = (const float*)d_in[3];
    const float* W_rec   = (const float*)d_in[4];
    const float* W_gate  = (const float*)d_in[5];
    const float* b_gate  = (const float*)d_in[6];
    const float* W_out   = (const float*)d_in[7];
    const float* b_out   = (const float*)d_in[8];

    float* out   = (float*)d_out;                       // (32,1024,512) fp32
    float* hlast = out + (size_t)LTC_B * LTC_L * LTC_H; // (32,512) fp32

    u32* ws    = (u32*)d_ws;                   // 64 MB + 128 KB used
    u32* drive = ws;                           // 8388608 u32 (f16 pairs)
    u32* gatex = ws + 8388608;                 // 8388608 u32
    u64* hbuf  = (u64*)(ws + 16777216);        // 16384 u64 stamped pairs

    const int blocks = (LTC_B * LTC_L / 64) * (LTC_H / 64) / 4;   // 1024

    gemm_a32_c16<<<blocks, 256, 0, stream>>>(x, W_in, LTC_D, b_in, (u16*)drive);
    gemm_a32_c16<<<blocks, 256, 0, stream>>>(x, W_gate, LTC_D + LTC_H, b_gate, (u16*)gatex);
    ltc_scan<<<NG * NP, 256, 0, stream>>>(drive, gatex, W_rec, W_gate, log_tau,
                                          hbuf, hlast);
    gemm_a16_c32<<<blocks, 256, 0, stream>>>((const u16*)drive, W_out, b_out, out);
}

// Round 4
// 10879.452 us; speedup vs baseline: 1.5118x; 1.5118x over previous
//
#include <hip/hip_runtime.h>

typedef unsigned short u16;
typedef unsigned int   u32;
typedef unsigned long long u64;

#define LTC_B 32
#define LTC_L 1024
#define LTC_D 512
#define LTC_H 512
#define NG 8               // groups
#define NP 16              // producer WGs per group (each owns 32+32 W rows)
#define NBG 4              // batches per group

typedef _Float16 f16x8  __attribute__((ext_vector_type(8)));
typedef _Float16 f16x2t __attribute__((ext_vector_type(2)));
typedef float    f32x4  __attribute__((ext_vector_type(4)));

static __device__ __forceinline__ u32 packh(float a, float b) {
    f16x2t p; p[0] = (_Float16)a; p[1] = (_Float16)b;
    return __builtin_bit_cast(u32, p);
}
static __device__ __forceinline__ float unplo(u32 w) {
    return (float)__builtin_bit_cast(f16x2t, w)[0];
}
static __device__ __forceinline__ float unphi(u32 w) {
    return (float)__builtin_bit_cast(f16x2t, w)[1];
}
static __device__ __forceinline__ float sigm(float x) {
    return 1.f / (1.f + __expf(-x));
}
static __device__ __forceinline__ float tanh_f(float x) {
    float e = __expf(2.f * x);          // inf-safe: e=inf -> 1, e=0 -> -1
    return 1.f - 2.f / (e + 1.f);
}
static __device__ __forceinline__ f16x8 cvt8(const float* p) {
    const float4 a = *(const float4*)p;
    const float4 b = *(const float4*)(p + 4);
    f16x8 r;
    r[0] = (_Float16)a.x; r[1] = (_Float16)a.y; r[2] = (_Float16)a.z; r[3] = (_Float16)a.w;
    r[4] = (_Float16)b.x; r[5] = (_Float16)b.y; r[6] = (_Float16)b.z; r[7] = (_Float16)b.w;
    return r;
}
static __device__ __forceinline__ bool stamp4(u64 a, u64 b, u64 c, u64 d, u32 k) {
    return ((u32)(a >> 32) == k) & ((u32)(b >> 32) == k) &
           ((u32)(c >> 32) == k) & ((u32)(d >> 32) == k);
}

// ---------------------------------------------------------------------------
// C[M,512](f16) = A[M,512](f32) . W[:,:512]^T(f32, row stride ldb) + bias(f32)
// ---------------------------------------------------------------------------
__global__ __launch_bounds__(256) void gemm_a32_c16(
    const float* __restrict__ A, const float* __restrict__ W, int ldb,
    const float* __restrict__ bias, u16* __restrict__ C)
{
    const int wave = threadIdx.x >> 6;
    const int lane = threadIdx.x & 63;
    const int tile = blockIdx.x * 4 + wave;
    const int nt = tile & 7;
    const int mt = tile >> 3;
    const int r16 = lane & 15;
    const int kq  = (lane >> 4) * 8;

    const float* ap = A + (size_t)(mt * 64 + r16) * LTC_D + kq;
    const float* wp = W + (size_t)(nt * 64 + r16) * ldb + kq;

    f32x4 acc[4][4];
    #pragma unroll
    for (int i = 0; i < 4; ++i)
        #pragma unroll
        for (int jj = 0; jj < 4; ++jj) acc[i][jj] = (f32x4){0.f, 0.f, 0.f, 0.f};

    for (int ks = 0; ks < 16; ++ks) {
        f16x8 af[4], bf[4];
        #pragma unroll
        for (int t = 0; t < 4; ++t) {
            af[t] = cvt8(ap + (size_t)t * 16 * LTC_D + ks * 32);
            bf[t] = cvt8(wp + (size_t)t * 16 * ldb  + ks * 32);
        }
        #pragma unroll
        for (int mi = 0; mi < 4; ++mi)
            #pragma unroll
            for (int ni = 0; ni < 4; ++ni)
                acc[mi][ni] = __builtin_amdgcn_mfma_f32_16x16x32_f16(
                    af[mi], bf[ni], acc[mi][ni], 0, 0, 0);
    }
    const int row = (lane >> 4) * 4;   // C/D: col=lane&15 (n), row=(lane>>4)*4+reg (m)
    const int col = lane & 15;
    #pragma unroll
    for (int ni = 0; ni < 4; ++ni) {
        const int n = nt * 64 + ni * 16 + col;
        const float bv = bias[n];
        #pragma unroll
        for (int mi = 0; mi < 4; ++mi)
            #pragma unroll
            for (int r = 0; r < 4; ++r) {
                _Float16 h = (_Float16)(acc[mi][ni][r] + bv);
                C[(size_t)(mt * 64 + mi * 16 + row + r) * LTC_H + n] =
                    __builtin_bit_cast(u16, h);
            }
    }
}

// ---------------------------------------------------------------------------
// C[M,512](f32) = A[M,512](f16) . W^T(f32, row stride 512) + bias(f32)
// ---------------------------------------------------------------------------
__global__ __launch_bounds__(256) void gemm_a16_c32(
    const u16* __restrict__ A, const float* __restrict__ W,
    const float* __restrict__ bias, float* __restrict__ C)
{
    const int wave = threadIdx.x >> 6;
    const int lane = threadIdx.x & 63;
    const int tile = blockIdx.x * 4 + wave;
    const int nt = tile & 7;
    const int mt = tile >> 3;
    const int r16 = lane & 15;
    const int kq  = (lane >> 4) * 8;

    const _Float16* ap = (const _Float16*)A + (size_t)(mt * 64 + r16) * LTC_D + kq;
    const float*    wp = W + (size_t)(nt * 64 + r16) * LTC_H + kq;

    f32x4 acc[4][4];
    #pragma unroll
    for (int i = 0; i < 4; ++i)
        #pragma unroll
        for (int jj = 0; jj < 4; ++jj) acc[i][jj] = (f32x4){0.f, 0.f, 0.f, 0.f};

    for (int ks = 0; ks < 16; ++ks) {
        f16x8 af[4], bf[4];
        #pragma unroll
        for (int t = 0; t < 4; ++t) {
            af[t] = *(const f16x8*)(ap + (size_t)t * 16 * LTC_D + ks * 32);
            bf[t] = cvt8(wp + (size_t)t * 16 * LTC_H + ks * 32);
        }
        #pragma unroll
        for (int mi = 0; mi < 4; ++mi)
            #pragma unroll
            for (int ni = 0; ni < 4; ++ni)
                acc[mi][ni] = __builtin_amdgcn_mfma_f32_16x16x32_f16(
                    af[mi], bf[ni], acc[mi][ni], 0, 0, 0);
    }
    const int row = (lane >> 4) * 4;
    const int col = lane & 15;
    #pragma unroll
    for (int ni = 0; ni < 4; ++ni) {
        const int n = nt * 64 + ni * 16 + col;
        const float bv = bias[n];
        #pragma unroll
        for (int mi = 0; mi < 4; ++mi)
            #pragma unroll
            for (int r = 0; r < 4; ++r)
                C[(size_t)(mt * 64 + mi * 16 + row + r) * LTC_H + n] =
                    acc[mi][ni][r] + bv;
    }
}

// ---------------------------------------------------------------------------
// ODE scan: 8 groups x 4 batches, 16 producer WGs per group (128 WGs).
// EXACT round-0 structure (best verified) + ONE edit: own-column LDS
// shortcut. Update threads write their fresh pair into hTu directly (LDS,
// barrier-ordered like the gather writes), and the 16 gather threads whose
// polled column belongs to THIS WG ((tid>>4)==p) skip the LLC poll — they
// no longer wait on our own store-ack -> LLC -> reload round-trip. Remote
// columns keep the VALIDATED LLC channel byte-identical: stamped u64
// (stamp<<32 | f16 pair), relaxed agent-scope publish, batched 4-load LLC
// poll sweep, bounded budget (protocol failure => wrong answer via absmax,
// never a hang). Waves 1-3 still enter the poll loop immediately after
// barrier #1 (dedicated early pollers — the property rounds 2/3 lost).
// ---------------------------------------------------------------------------
__global__ __launch_bounds__(256) void ltc_scan(
    u32* __restrict__ drive,            // f16 pairs; rewritten with fwd
    const u32* __restrict__ gatex,      // f16 pairs
    const float* __restrict__ W_rec,
    const float* __restrict__ W_gate,
    const float* __restrict__ log_tau,
    u64* __restrict__ hbuf,             // [2 par][8 g][4 b][256] stamped pairs
    float* __restrict__ hlast)
{
    const int g   = blockIdx.x & 7;     // group
    const int p   = blockIdx.x >> 3;    // producer slice 0..15
    const int tid = threadIdx.x;
    const int lane = tid & 63;
    const int wv   = tid >> 6;          // n-tile: 0-1 rec rows, 2-3 gate rows

    __shared__ u32 hTu[16][260];        // h as f16 pairs; rows 0-3 = batches
    __shared__ float red[64][17];       // matvec results [n][m]

    // ---- one-time: B-fragments (my 32 W_rec + 32 Wg_h rows) into registers
    const int nl = wv * 16 + (lane & 15);      // 0..63
    const int kq = (lane >> 4) * 8;
    const float* wrow = (nl < 32)
        ? (W_rec  + (size_t)(32 * p + nl) * LTC_H)
        : (W_gate + (size_t)(32 * p + nl - 32) * (LTC_D + LTC_H) + LTC_D);
    f16x8 Wf[16];
    #pragma unroll
    for (int ks = 0; ks < 16; ++ks) Wf[ks] = cvt8(wrow + ks * 32 + kq);

    for (int i = tid; i < 16 * 260; i += 256) (&hTu[0][0])[i] = 0;  // h0 = 0
    __syncthreads();

    // ---- update-thread setup (wave 0 only: 4 b x 16 pairs = 64 threads)
    const int ub = tid >> 4;            // local batch (tid<64)
    const int jp = tid & 15;
    const int j0 = 32 * p + 2 * jp;
    const int gb = g * NBG + ub;        // global batch
    float h0 = 0.f, h1 = 0.f, stau0 = 0.f, stau1 = 0.f;
    size_t dwofs = 0;
    if (tid < 64) {
        stau0 = (1.f / 6.f) * __expf(-log_tau[j0]);
        stau1 = (1.f / 6.f) * __expf(-log_tau[j0 + 1]);
        dwofs = (size_t)gb * LTC_L * 256 + 16 * p + jp;
    }

    const _Float16* hrow = (const _Float16*)&hTu[lane & 15][0];
    u32 kp1 = 0;
    int budget = 1 << 22;               // global failing-poll budget (no hangs)
    const bool own = ((tid >> 4) == p); // my polled column is published by MY WG

    // prime l=0 inputs
    u32 dw = 0, gw = 0;
    if (tid < 64) { dw = drive[dwofs]; gw = gatex[dwofs]; }

    for (int l = 0; l < LTC_L; ++l) {
        const float d0 = unplo(dw), d1 = unphi(dw);
        const float gx0 = unplo(gw), gx1 = unphi(gw);
        // prefetch next step's inputs (overlaps with 6 sub-steps of work)
        u32 dn = 0, gn = 0;
        if (tid < 64 && l + 1 < LTC_L) {
            dn = drive[dwofs + (size_t)(l + 1) * 256];
            gn = gatex[dwofs + (size_t)(l + 1) * 256];
        }
        #pragma unroll 1
        for (int s = 0; s < 6; ++s) {
            // ---- matvec: red[n][m] = sum_k h[m,k] * Wrow(n)[k] (2 acc chains)
            f32x4 acc0 = (f32x4){0.f, 0.f, 0.f, 0.f}, acc1 = acc0;
            #pragma unroll
            for (int ks = 0; ks < 16; ks += 2) {
                const f16x8 a0 = *(const f16x8*)(hrow + ks * 32 + kq);
                const f16x8 a1 = *(const f16x8*)(hrow + (ks + 1) * 32 + kq);
                acc0 = __builtin_amdgcn_mfma_f32_16x16x32_f16(a0, Wf[ks],     acc0, 0, 0, 0);
                acc1 = __builtin_amdgcn_mfma_f32_16x16x32_f16(a1, Wf[ks + 1], acc1, 0, 0, 0);
            }
            {
                const int n  = wv * 16 + (lane & 15);
                const int rb = (lane >> 4) * 4;
                #pragma unroll
                for (int r = 0; r < 4; ++r) red[n][rb + r] = acc0[r] + acc1[r];
            }
            __syncthreads();
            ++kp1;
            const size_t pbase = (size_t)((kp1 & 1u) * NG + g) * (NBG * 256);
            // ---- update + own-column LDS write + single LLC publish --------
            if (tid < 64) {
                const float rec0 = red[2 * jp][ub],     gh0 = red[32 + 2 * jp][ub];
                const float rec1 = red[2 * jp + 1][ub], gh1 = red[32 + 2 * jp + 1][ub];
                h0 += stau0 * (sigm(gx0 + gh0) * tanh_f(d0 + rec0) - h0);
                h1 += stau1 * (sigm(gx1 + gh1) * tanh_f(d1 + rec1) - h1);
                const u32 pr = packh(h0, h1);
                hTu[ub][16 * p + jp] = pr;      // own column: LDS shortcut
                const u64 v = ((u64)kp1 << 32) | (u64)pr;
                __hip_atomic_store(hbuf + pbase + (size_t)ub * 256 + 16 * p + jp,
                                   v, __ATOMIC_RELAXED, __HIP_MEMORY_SCOPE_AGENT);
            }
            // ---- gather: remote columns only, batched LLC sweep ------------
            if (!own) {
                const u64* sb = hbuf + pbase + tid;
                u64 a0, a1, a2, a3;
                bool ok;
                do {
                    a0 = __hip_atomic_load(sb,       __ATOMIC_RELAXED,
                                           __HIP_MEMORY_SCOPE_AGENT);
                    a1 = __hip_atomic_load(sb + 256, __ATOMIC_RELAXED,
                                           __HIP_MEMORY_SCOPE_AGENT);
                    a2 = __hip_atomic_load(sb + 512, __ATOMIC_RELAXED,
                                           __HIP_MEMORY_SCOPE_AGENT);
                    a3 = __hip_atomic_load(sb + 768, __ATOMIC_RELAXED,
                                           __HIP_MEMORY_SCOPE_AGENT);
                    ok = stamp4(a0, a1, a2, a3, kp1);
                } while (!ok && --budget > 0);
                hTu[0][tid] = (u32)a0; hTu[1][tid] = (u32)a1;
                hTu[2][tid] = (u32)a2; hTu[3][tid] = (u32)a3;
            }
            __syncthreads();
        }
        if (tid < 64) drive[dwofs + (size_t)l * 256] = packh(h0, h1);  // fwd
        dw = dn; gw = gn;
    }
    if (tid < 64) {
        hlast[(size_t)gb * LTC_H + j0]     = h0;
        hlast[(size_t)gb * LTC_H + j0 + 1] = h1;
    }
}

// ---------------------------------------------------------------------------
extern "C" void kernel_launch(void* const* d_in, const int* in_sizes, int n_in,
                              void* d_out, int out_size, void* d_ws, size_t ws_size,
                              hipStream_t stream)
{
    const float* x       = (const float*)d_in[0];
    const float* log_tau = (const float*)d_in[1];
    const float* W_in    = (const float*)d_in[2];
    const float* b_in    = (const float*)d_in[3];
    const float* W_rec   = (const float*)d_in[4];
    const float* W_gate  = (const float*)d_in[5];
    const float* b_gate  = (const float*)d_in[6];
    const float* W_out   = (const float*)d_in[7];
    const float* b_out   = (const float*)d_in[8];

    float* out   = (float*)d_out;                       // (32,1024,512) fp32
    float* hlast = out + (size_t)LTC_B * LTC_L * LTC_H; // (32,512) fp32

    u32* ws    = (u32*)d_ws;                   // 64 MB + 128 KB used
    u32* drive = ws;                           // 8388608 u32 (f16 pairs)
    u32* gatex = ws + 8388608;                 // 8388608 u32
    u64* hbuf  = (u64*)(ws + 16777216);        // 16384 u64 stamped pairs

    const int blocks = (LTC_B * LTC_L / 64) * (LTC_H / 64) / 4;   // 1024

    gemm_a32_c16<<<blocks, 256, 0, stream>>>(x, W_in, LTC_D, b_in, (u16*)drive);
    gemm_a32_c16<<<blocks, 256, 0, stream>>>(x, W_gate, LTC_D + LTC_H, b_gate, (u16*)gatex);
    ltc_scan<<<NG * NP, 256, 0, stream>>>(drive, gatex, W_rec, W_gate, log_tau,
                                          hbuf, hlast);
    gemm_a16_c32<<<blocks, 256, 0, stream>>>((const u16*)drive, W_out, b_out, out);
}